// Round 7
// baseline (858.618 us; speedup 1.0000x reference)
//
#include <hip/hip_runtime.h>
#include <math.h>

// LSTM B=8192,T=512,IN=3,H=32,OUT=2 fp32.
// R7: R6's two independent 4-batch groups per wave (1024 waves = 1/SIMD),
// restructured as an explicit 2-stage software pipeline:
//   loop t: [MFMA(G1,t) || tail(G0,t)] ; [MFMA(G0,t+1) || tail(G1,t)]
// with __builtin_amdgcn_sched_group_barrier enforcing ~1 MFMA : 4 VALU
// interleave so the in-order wave never serializes an MFMA burst against
// its own tail (R6's failure mode). B(t=0)=0 => prologue accs are zero.
// Per-group layout = R5: batches replicated in 4 column-quadrants, replicas
// split the 8 units 4-ways -> 2 units/lane/group; x-preacts exact fp32 VALU
// added post-MFMA. Zero LDS, zero barriers.
// Weights pre-scaled by -log2e (-2log2e for g) -> raw v_exp_f32.

namespace {
constexpr int   kT   = 512;
constexpr float kL2E = 1.44269504088896340736f;
}

typedef __bf16 bf16x8 __attribute__((ext_vector_type(8)));
typedef float  f32x4  __attribute__((ext_vector_type(4)));

union Frag {
    bf16x8 v;
    unsigned short u[8];
    unsigned int   d[4];
};

__device__ __forceinline__ unsigned short bf_rne(float f) {
    unsigned u = __float_as_uint(f);
    u += 0x7fffu + ((u >> 16) & 1u);
    return (unsigned short)(u >> 16);
}
__device__ __forceinline__ float bf_tof(unsigned short h) {
    return __uint_as_float((unsigned)h << 16);
}
__device__ __forceinline__ float fast_exp2(float v) { return __builtin_amdgcn_exp2f(v); }
__device__ __forceinline__ float fast_rcp(float v)  { return __builtin_amdgcn_rcpf(v); }
__device__ __forceinline__ unsigned pck(unsigned short a, unsigned short b) {
    return (unsigned)a | ((unsigned)b << 16);
}

#define MFMA16 __builtin_amdgcn_mfma_f32_16x16x32_bf16

extern "C" __global__ __launch_bounds__(256, 1)
void lstm_pipe(const float* __restrict__ x,
               const float* __restrict__ W_ih,
               const float* __restrict__ W_hh,
               const float* __restrict__ b_ih,
               const float* __restrict__ b_hh,
               const float* __restrict__ W_fc,
               const float* __restrict__ b_fc,
               float* __restrict__ out) {
    const int lane = threadIdx.x & 63;
    const int wv   = threadIdx.x >> 6;          // wave in block, 0..3
    const int gw   = blockIdx.x * 4 + wv;       // global wave id, 0..1023
    const int n    = lane & 15;                 // B/D column
    const int q    = lane >> 4;                 // quad
    const int bat  = n & 3;                     // batch within group
    const int rh   = (n >> 2) & 1;              // reg-pair selector
    const int p    = (n >> 3) & 1;              // chunk-parity selector
    const bool prh = (rh != 0);
    const bool pp1 = (p != 0);

    // ---- shared A-frags: permuted scaled W_hh (hi/lo) ----
    // chunk cc (g=cc>>1, pc=cc&1): A row m holds W row
    // R = 32g + 8(m>>2) + 4pc + (m&3) => D row 4q+r = gate g, unit 8q+4pc+r.
    Frag Ah[8], Al[8];
#pragma unroll
    for (int cc = 0; cc < 8; ++cc) {
        const int   g  = cc >> 1, pc = cc & 1;
        const float s  = (g == 2) ? -2.0f * kL2E : -kL2E;
        const int   R  = 32 * g + 8 * (n >> 2) + 4 * pc + (n & 3);
#pragma unroll
        for (int j = 0; j < 8; ++j) {
            const float w = W_hh[R * 32 + 8 * q + j] * s;
            const unsigned short hb = bf_rne(w);
            Ah[cc].u[j] = hb;
            Al[cc].u[j] = bf_rne(w - bf_tof(hb));
        }
    }

    // ---- shared per-lane x-path constants (my units u0, u0+1) ----
    const int u0 = 8 * q + 4 * p + 2 * rh;
    float xw[4][2][3], xbias[4][2];
#pragma unroll
    for (int g = 0; g < 4; ++g) {
        const float s = (g == 2) ? -2.0f * kL2E : -kL2E;
#pragma unroll
        for (int j2 = 0; j2 < 2; ++j2) {
            const int R = 32 * g + u0 + j2;
#pragma unroll
            for (int k = 0; k < 3; ++k) xw[g][j2][k] = W_ih[R * 3 + k] * s;
            xbias[g][j2] = (b_ih[R] + b_hh[R]) * s;
        }
    }

    // ---- per-group state ----
    const float* xb0;
    const float* xb1;
    float cst[2][2], hfull[2][2], xc[2][3];
    Frag Bh[2], Bl[2];
    {
        const int b0 = gw * 8 + 0 * 4 + bat;
        const int b1 = gw * 8 + 1 * 4 + bat;
        xb0 = x + (size_t)b0 * kT * 3;
        xb1 = x + (size_t)b1 * kT * 3;
    }
#pragma unroll
    for (int gi = 0; gi < 2; ++gi) {
        cst[gi][0] = cst[gi][1] = 0.f;
        hfull[gi][0] = hfull[gi][1] = 0.f;
#pragma unroll
        for (int j = 0; j < 4; ++j) { Bh[gi].d[j] = 0; Bl[gi].d[j] = 0; }
    }
    xc[0][0] = xb0[0]; xc[0][1] = xb0[1]; xc[0][2] = xb0[2];
    xc[1][0] = xb1[0]; xc[1][1] = xb1[1]; xc[1][2] = xb1[2];

    // tail: consume acc -> update c/h, rebuild B-frags, advance xc
    auto tail = [&](int gi, const f32x4 (&acc)[8], const float* xbp, int t) {
        // exact fp32 x-preacts (off the MFMA path)
        float xp[4][2];
#pragma unroll
        for (int g = 0; g < 4; ++g)
#pragma unroll
            for (int j2 = 0; j2 < 2; ++j2)
                xp[g][j2] = fmaf(xc[gi][0], xw[g][j2][0],
                            fmaf(xc[gi][1], xw[g][j2][1],
                            fmaf(xc[gi][2], xw[g][j2][2], xbias[g][j2])));

        const int tn = (t + 1 < kT) ? t + 1 : t;
        const float xn0 = xbp[tn * 3 + 0];
        const float xn1 = xbp[tn * 3 + 1];
        const float xn2 = xbp[tn * 3 + 2];

        float P[4][2];
#pragma unroll
        for (int g = 0; g < 4; ++g) {
#pragma unroll
            for (int j2 = 0; j2 < 2; ++j2) {
                const float ve = prh ? acc[2 * g + 0][2 + j2] : acc[2 * g + 0][j2];
                const float vo = prh ? acc[2 * g + 1][2 + j2] : acc[2 * g + 1][j2];
                P[g][j2] = (pp1 ? vo : ve) + xp[g][j2];
            }
        }

        unsigned short hh[2], hl[2];
#pragma unroll
        for (int j2 = 0; j2 < 2; ++j2) {
            const float Ei = fast_exp2(P[0][j2]);
            const float Ef = fast_exp2(P[1][j2]);
            float       Eg = fast_exp2(P[2][j2]);
            const float Eo = fast_exp2(P[3][j2]);
            Eg = fminf(Eg, 1e30f);
            const float sf  = fast_rcp(1.0f + Ef);
            const float dig = fast_rcp((1.0f + Ei) * (1.0f + Eg));
            const float ig  = (1.0f - Eg) * dig;
            const float c   = fmaf(sf, cst[gi][j2], ig);
            cst[gi][j2] = c;
            float Ec = fast_exp2(c * (-2.0f * kL2E));
            Ec = fminf(Ec, 1e30f);
            const float doc = fast_rcp((1.0f + Eo) * (1.0f + Ec));
            const float h   = (1.0f - Ec) * doc;
            hfull[gi][j2] = h;
            hh[j2] = bf_rne(h);
            hl[j2] = bf_rne(h - bf_tof(hh[j2]));
        }

        const unsigned myhi = pck(hh[0], hh[1]);
        const unsigned mylo = pck(hl[0], hl[1]);
        const unsigned othi = __shfl_xor(myhi, 4, 64);
        const unsigned otlo = __shfl_xor(mylo, 4, 64);
        const unsigned eA = prh ? othi : myhi;
        const unsigned eB = prh ? myhi : othi;
        const unsigned eC = prh ? otlo : mylo;
        const unsigned eD = prh ? mylo : otlo;
        const unsigned fA = __shfl_xor(eA, 8, 64);
        const unsigned fB = __shfl_xor(eB, 8, 64);
        const unsigned fC = __shfl_xor(eC, 8, 64);
        const unsigned fD = __shfl_xor(eD, 8, 64);
        Bh[gi].d[0] = pp1 ? fA : eA;
        Bh[gi].d[1] = pp1 ? fB : eB;
        Bh[gi].d[2] = pp1 ? eA : fA;
        Bh[gi].d[3] = pp1 ? eB : fB;
        Bl[gi].d[0] = pp1 ? fC : eC;
        Bl[gi].d[1] = pp1 ? fD : eD;
        Bl[gi].d[2] = pp1 ? eC : fC;
        Bl[gi].d[3] = pp1 ? eD : fD;

        xc[gi][0] = xn0; xc[gi][1] = xn1; xc[gi][2] = xn2;
    };

    // ---- software pipeline ----
    // B(t=0) = 0 for both groups => acc0(t=0) = 0 without issuing MFMAs.
    f32x4 acc0[8], acc1[8];
    const f32x4 z = {0.f, 0.f, 0.f, 0.f};
#pragma unroll
    for (int cc = 0; cc < 8; ++cc) acc0[cc] = z;

    for (int t = 0; t < kT; ++t) {
        // Half A: MFMA(G1, t) interleaved with tail(G0, t)
        if (t == 0) {
#pragma unroll
            for (int cc = 0; cc < 8; ++cc) acc1[cc] = z;
        } else {
#pragma unroll
            for (int cc = 0; cc < 8; ++cc) acc1[cc] = MFMA16(Ah[cc].v, Bh[1].v, z, 0, 0, 0);
#pragma unroll
            for (int cc = 0; cc < 8; ++cc) acc1[cc] = MFMA16(Al[cc].v, Bh[1].v, acc1[cc], 0, 0, 0);
#pragma unroll
            for (int cc = 0; cc < 8; ++cc) acc1[cc] = MFMA16(Ah[cc].v, Bl[1].v, acc1[cc], 0, 0, 0);
        }
        tail(0, acc0, xb0, t);

        // Half B: MFMA(G0, t+1) interleaved with tail(G1, t)
#pragma unroll
        for (int cc = 0; cc < 8; ++cc) acc0[cc] = MFMA16(Ah[cc].v, Bh[0].v, z, 0, 0, 0);
#pragma unroll
        for (int cc = 0; cc < 8; ++cc) acc0[cc] = MFMA16(Al[cc].v, Bh[0].v, acc0[cc], 0, 0, 0);
#pragma unroll
        for (int cc = 0; cc < 8; ++cc) acc0[cc] = MFMA16(Ah[cc].v, Bl[0].v, acc0[cc], 0, 0, 0);
        tail(1, acc1, xb1, t);

#if __has_builtin(__builtin_amdgcn_sched_group_barrier)
        // Interleave request: ~1 MFMA : 4 VALU (+ DS / TRANS sprinkled)
#pragma unroll
        for (int i = 0; i < 48; ++i) {
            __builtin_amdgcn_sched_group_barrier(0x008, 1, 0);  // 1 MFMA
            __builtin_amdgcn_sched_group_barrier(0x002, 4, 0);  // 4 VALU
            if ((i & 3) == 0)
                __builtin_amdgcn_sched_group_barrier(0x080, 1, 0);  // 1 DS
            if ((i & 1) == 0)
                __builtin_amdgcn_sched_group_barrier(0x400, 1, 0);  // 1 TRANS
        }
#endif
    }

    // ---- epilogue per group ----
#pragma unroll
    for (int gi = 0; gi < 2; ++gi) {
        float s0 = 0.f, s1 = 0.f;
#pragma unroll
        for (int j2 = 0; j2 < 2; ++j2) {
            const int u = u0 + j2;
            s0 = fmaf(hfull[gi][j2], W_fc[u], s0);
            s1 = fmaf(hfull[gi][j2], W_fc[32 + u], s1);
        }
        s0 += __shfl_xor(s0, 4, 64);  s1 += __shfl_xor(s1, 4, 64);
        s0 += __shfl_xor(s0, 8, 64);  s1 += __shfl_xor(s1, 8, 64);
        s0 += __shfl_xor(s0, 16, 64); s1 += __shfl_xor(s1, 16, 64);
        s0 += __shfl_xor(s0, 32, 64); s1 += __shfl_xor(s1, 32, 64);
        if (lane < 4) {
            const int b = gw * 8 + gi * 4 + bat;
            out[(size_t)b * 2 + 0] = s0 + b_fc[0];
            out[(size_t)b * 2 + 1] = s1 + b_fc[1];
        }
    }
}

extern "C" void kernel_launch(void* const* d_in, const int* in_sizes, int n_in,
                              void* d_out, int out_size, void* d_ws, size_t ws_size,
                              hipStream_t stream) {
    const float* x    = (const float*)d_in[0];
    const float* W_ih = (const float*)d_in[1];
    const float* W_hh = (const float*)d_in[2];
    const float* b_ih = (const float*)d_in[3];
    const float* b_hh = (const float*)d_in[4];
    const float* W_fc = (const float*)d_in[5];
    const float* b_fc = (const float*)d_in[6];
    float* out = (float*)d_out;

    const int batch = in_sizes[0] / (kT * 3);   // 8192
    dim3 grid(batch / 32);                      // 256 blocks (1 per CU)
    dim3 block(256);                            // 4 waves -> 1 per SIMD
    hipLaunchKernelGGL(lstm_pipe, grid, block, 0, stream,
                       x, W_ih, W_hh, b_ih, b_hh, W_fc, b_fc, out);
}

// Round 8
// 404.691 us; speedup vs baseline: 2.1217x; 2.1217x over previous
//
#include <hip/hip_runtime.h>
#include <math.h>

// LSTM B=8192,T=512,IN=3,H=32,OUT=2 fp32.
// R8: 8 batches/wave, 2-fold column replication (cols 0-7 == cols 8-15),
// 1024 waves = 1 per SIMD on ALL 1024 SIMDs. Lane pair (n, n+8) splits the
// 8 units of each q-group 4/4 -> 4-unit tails (32 trans-instr/step/wave),
// 24 MFMA/step/wave (466 port-cyc/SIMD, half of R5). B-rebuild: 4 shfl_xor
// + 8 selects. x-preacts exact fp32 VALU off the MFMA path. hi/lo packing
// via truncation + v_perm_b32 (residual goes into the lo term). Zero LDS,
// zero barriers. Weights pre-scaled by -log2e (-2log2e for g) -> raw exp2.

namespace {
constexpr int   kT   = 512;
constexpr float kL2E = 1.44269504088896340736f;
}

typedef __bf16 bf16x8 __attribute__((ext_vector_type(8)));
typedef float  f32x4  __attribute__((ext_vector_type(4)));

union Frag {
    bf16x8 v;
    unsigned short u[8];
    unsigned int   d[4];
};

__device__ __forceinline__ unsigned short bf_rne(float f) {
    unsigned u = __float_as_uint(f);
    u += 0x7fffu + ((u >> 16) & 1u);
    return (unsigned short)(u >> 16);
}
__device__ __forceinline__ float bf_tof(unsigned short h) {
    return __uint_as_float((unsigned)h << 16);
}
__device__ __forceinline__ float fast_exp2(float v) { return __builtin_amdgcn_exp2f(v); }
__device__ __forceinline__ float fast_rcp(float v)  { return __builtin_amdgcn_rcpf(v); }

// pack the high-16 bits (bf16 truncation) of two fp32 into one dword:
// result = [lo16 = a.hi16, hi16 = b.hi16]
__device__ __forceinline__ unsigned pack_hi16(float a, float b) {
    return __builtin_amdgcn_perm(__float_as_uint(b), __float_as_uint(a), 0x07060302u);
}

#define MFMA16 __builtin_amdgcn_mfma_f32_16x16x32_bf16

extern "C" __global__ __launch_bounds__(64, 1)
void lstm_rep2(const float* __restrict__ x,
               const float* __restrict__ W_ih,
               const float* __restrict__ W_hh,
               const float* __restrict__ b_ih,
               const float* __restrict__ b_hh,
               const float* __restrict__ W_fc,
               const float* __restrict__ b_fc,
               float* __restrict__ out) {
    const int  lane = threadIdx.x & 63;
    const int  n    = lane & 15;        // B/D column == A row
    const int  q    = lane >> 4;        // quad
    const int  pp   = (n >> 3) & 1;     // replica half: 0 -> units +0..3, 1 -> +4..7
    const int  bat  = n & 7;            // batch within wave
    const int  b    = blockIdx.x * 8 + bat;
    const bool isP  = (pp != 0);

    // ---- A-frags: permuted scaled W_hh (hi/lo) ----
    // chunk cc (g=cc>>1, pc=cc&1): A row m holds W row
    // R = 32g + 8(m>>2) + 4pc + (m&3)  =>  D row 4q+r of chunk cc is
    // gate g, unit u = 8q + 4pc + r (verified R3/R5).
    Frag Ah[8], Al[8];
#pragma unroll
    for (int cc = 0; cc < 8; ++cc) {
        const int   g  = cc >> 1, pc = cc & 1;
        const float s  = (g == 2) ? -2.0f * kL2E : -kL2E;
        const int   R  = 32 * g + 8 * (n >> 2) + 4 * pc + (n & 3);
#pragma unroll
        for (int j = 0; j < 8; ++j) {
            const float w = W_hh[R * 32 + 8 * q + j] * s;
            const unsigned short hb = bf_rne(w);
            Ah[cc].u[j] = hb;
            Al[cc].u[j] = bf_rne(w - bf_tof(hb));
        }
    }

    // ---- per-lane x-path constants for my 4 units (u0..u0+3) x 4 gates ----
    const int u0 = 8 * q + 4 * pp;
    float xw[4][4][3], xbias[4][4];
#pragma unroll
    for (int g = 0; g < 4; ++g) {
        const float s = (g == 2) ? -2.0f * kL2E : -kL2E;
#pragma unroll
        for (int r = 0; r < 4; ++r) {
            const int R = 32 * g + u0 + r;
#pragma unroll
            for (int k = 0; k < 3; ++k) xw[g][r][k] = W_ih[R * 3 + k] * s;
            xbias[g][r] = (b_ih[R] + b_hh[R]) * s;
        }
    }

    const float* xb = x + (size_t)b * kT * 3;

    float cst[4]   = {0.f, 0.f, 0.f, 0.f};
    float hfull[4] = {0.f, 0.f, 0.f, 0.f};
    Frag Bh, Bl;
#pragma unroll
    for (int j = 0; j < 4; ++j) { Bh.d[j] = 0; Bl.d[j] = 0; }

    float xc0 = xb[0], xc1 = xb[1], xc2 = xb[2];

    for (int t = 0; t < kT; ++t) {
        // ---- 24 MFMA: 3 passes x 8 chunks (8 independent depth-3 chains) ----
        f32x4 acc[8];
        const f32x4 z = {0.f, 0.f, 0.f, 0.f};
#pragma unroll
        for (int cc = 0; cc < 8; ++cc) acc[cc] = MFMA16(Ah[cc].v, Bh.v, z, 0, 0, 0);
#pragma unroll
        for (int cc = 0; cc < 8; ++cc) acc[cc] = MFMA16(Al[cc].v, Bh.v, acc[cc], 0, 0, 0);
#pragma unroll
        for (int cc = 0; cc < 8; ++cc) acc[cc] = MFMA16(Ah[cc].v, Bl.v, acc[cc], 0, 0, 0);

        // ---- exact fp32 x-preacts (independent of acc; fills MFMA shadow) ----
        float xp[4][4];
#pragma unroll
        for (int g = 0; g < 4; ++g)
#pragma unroll
            for (int r = 0; r < 4; ++r)
                xp[g][r] = fmaf(xc0, xw[g][r][0],
                           fmaf(xc1, xw[g][r][1],
                           fmaf(xc2, xw[g][r][2], xbias[g][r])));

        // prefetch next x
        const int tn = (t + 1 < kT) ? t + 1 : t;
        const float xn0 = xb[tn * 3 + 0];
        const float xn1 = xb[tn * 3 + 1];
        const float xn2 = xb[tn * 3 + 2];

        // ---- c/h update for my 4 units: P[g] = select(acc) + xp ----
        float hv[4];
#pragma unroll
        for (int r = 0; r < 4; ++r) {
            const float P0 = (isP ? acc[1][r] : acc[0][r]) + xp[0][r];
            const float P1 = (isP ? acc[3][r] : acc[2][r]) + xp[1][r];
            const float P2 = (isP ? acc[5][r] : acc[4][r]) + xp[2][r];
            const float P3 = (isP ? acc[7][r] : acc[6][r]) + xp[3][r];
            const float Ei = fast_exp2(P0);
            const float Ef = fast_exp2(P1);
            const float Eg = fast_exp2(P2);
            const float Eo = fast_exp2(P3);
            const float sf  = fast_rcp(1.0f + Ef);
            const float dig = fast_rcp((1.0f + Ei) * (1.0f + Eg));
            const float ig  = (1.0f - Eg) * dig;
            const float c   = fmaf(sf, cst[r], ig);
            cst[r] = c;
            float Ec = fast_exp2(c * (-2.0f * kL2E));
            Ec = fminf(Ec, 1e30f);                       // only overflow risk
            const float doc = fast_rcp((1.0f + Eo) * (1.0f + Ec));
            const float h   = (1.0f - Ec) * doc;
            hfull[r] = h;
            hv[r] = h;
        }

        // ---- hi/lo packing: truncate-high via v_perm, residual -> lo ----
        const unsigned hh01 = pack_hi16(hv[0], hv[1]);
        const unsigned hh23 = pack_hi16(hv[2], hv[3]);
        const float l0 = hv[0] - __uint_as_float(__float_as_uint(hv[0]) & 0xFFFF0000u);
        const float l1 = hv[1] - __uint_as_float(__float_as_uint(hv[1]) & 0xFFFF0000u);
        const float l2 = hv[2] - __uint_as_float(__float_as_uint(hv[2]) & 0xFFFF0000u);
        const float l3 = hv[3] - __uint_as_float(__float_as_uint(hv[3]) & 0xFFFF0000u);
        const unsigned hl01 = pack_hi16(l0, l1);
        const unsigned hl23 = pack_hi16(l2, l3);

        // ---- partner exchange (lane^8) + B assembly ----
        const unsigned ohh01 = __shfl_xor(hh01, 8, 64);
        const unsigned ohh23 = __shfl_xor(hh23, 8, 64);
        const unsigned ohl01 = __shfl_xor(hl01, 8, 64);
        const unsigned ohl23 = __shfl_xor(hl23, 8, 64);
        // k-slots j=0..3 = units 8q..8q+3 (pc=0 lane), j=4..7 = units +4..7
        Bh.d[0] = isP ? ohh01 : hh01;
        Bh.d[1] = isP ? ohh23 : hh23;
        Bh.d[2] = isP ? hh01 : ohh01;
        Bh.d[3] = isP ? hh23 : ohh23;
        Bl.d[0] = isP ? ohl01 : hl01;
        Bl.d[1] = isP ? ohl23 : hl23;
        Bl.d[2] = isP ? hl01 : ohl01;
        Bl.d[3] = isP ? hl23 : ohl23;

        xc0 = xn0; xc1 = xn1; xc2 = xn2;
    }

    // ---- epilogue: out[b][o] = sum_u h_u W_fc[o][u] + b_fc[o] ----
    float s0 = 0.f, s1 = 0.f;
#pragma unroll
    for (int r = 0; r < 4; ++r) {
        const int u = u0 + r;
        s0 = fmaf(hfull[r], W_fc[u], s0);
        s1 = fmaf(hfull[r], W_fc[32 + u], s1);
    }
    // combine replica halves (xor8) and quads (xor16, xor32)
    s0 += __shfl_xor(s0, 8, 64);  s1 += __shfl_xor(s1, 8, 64);
    s0 += __shfl_xor(s0, 16, 64); s1 += __shfl_xor(s1, 16, 64);
    s0 += __shfl_xor(s0, 32, 64); s1 += __shfl_xor(s1, 32, 64);
    if (lane < 8) {
        out[(size_t)b * 2 + 0] = s0 + b_fc[0];
        out[(size_t)b * 2 + 1] = s1 + b_fc[1];
    }
}

extern "C" void kernel_launch(void* const* d_in, const int* in_sizes, int n_in,
                              void* d_out, int out_size, void* d_ws, size_t ws_size,
                              hipStream_t stream) {
    const float* x    = (const float*)d_in[0];
    const float* W_ih = (const float*)d_in[1];
    const float* W_hh = (const float*)d_in[2];
    const float* b_ih = (const float*)d_in[3];
    const float* b_hh = (const float*)d_in[4];
    const float* W_fc = (const float*)d_in[5];
    const float* b_fc = (const float*)d_in[6];
    float* out = (float*)d_out;

    const int batch = in_sizes[0] / (kT * 3);   // 8192
    dim3 grid(batch / 8);                       // 1024 blocks, 1 wave each
    dim3 block(64);                             // -> 1 wave per SIMD, all SIMDs
    hipLaunchKernelGGL(lstm_rep2, grid, block, 0, stream,
                       x, W_ih, W_hh, b_ih, b_hh, W_fc, b_fc, out);
}